// Round 7
// baseline (306.942 us; speedup 1.0000x reference)
//
#include <hip/hip_runtime.h>
#include <hip/hip_bf16.h>
#include <cstdint>

typedef __bf16 bf16_t;
typedef __attribute__((ext_vector_type(8))) __bf16 bf16x8;
typedef __attribute__((ext_vector_type(4))) __bf16 bf16x4;
typedef __attribute__((ext_vector_type(4))) float f32x4;

#define S_LEN 2048
#define D_MODEL 2048
#define NH 16
#define NKV 4
#define HD_ 128

#define MFMA16(a, b, c) __builtin_amdgcn_mfma_f32_16x16x32_bf16((a), (b), (c), 0, 0, 0)

// Async global->LDS, 16B per lane. LDS dest must be WAVE-UNIFORM base; HW adds lane*16.
__device__ __forceinline__ void gload_lds16(const void* g, void* l) {
  __builtin_amdgcn_global_load_lds((__attribute__((address_space(1))) void*)((void*)g),
                                   (__attribute__((address_space(3))) void*)(l), 16, 0, 0);
}

// ---------------------------------------------------------------- prep kernels
__global__ __launch_bounds__(256) void cast_x_kernel(const float* __restrict__ in,
                                                     bf16_t* __restrict__ out, int n8) {
  int i = blockIdx.x * 256 + threadIdx.x;
  if (i >= n8) return;
  float4 a = reinterpret_cast<const float4*>(in)[2 * i];
  float4 b = reinterpret_cast<const float4*>(in)[2 * i + 1];
  bf16x8 o = {(__bf16)a.x, (__bf16)a.y, (__bf16)a.z, (__bf16)a.w,
              (__bf16)b.x, (__bf16)b.y, (__bf16)b.z, (__bf16)b.w};
  *reinterpret_cast<bf16x8*>(out + (size_t)i * 8) = o;
}

// in: [R][C] fp32 (ld=ldin) -> out: [C][R] bf16 (ld=ldout). 64x64 tile, 256 threads.
// grid = (C/64, R/64). float4 loads, bf16x8 stores.
__global__ __launch_bounds__(256) void transpose_cast64_kernel(const float* __restrict__ in,
    bf16_t* __restrict__ out, int ldin, int ldout) {
  __shared__ float t[64][65];
  const int c0 = blockIdx.x * 64, r0 = blockIdx.y * 64;
  const int rr = threadIdx.x >> 4;          // 0..15
  const int cc = (threadIdx.x & 15) * 4;    // 0..60
#pragma unroll
  for (int p = 0; p < 4; ++p) {
    int r = rr + p * 16;
    float4 v = *reinterpret_cast<const float4*>(in + (size_t)(r0 + r) * ldin + c0 + cc);
    t[r][cc] = v.x; t[r][cc + 1] = v.y; t[r][cc + 2] = v.z; t[r][cc + 3] = v.w;
  }
  __syncthreads();
  const int c = threadIdx.x >> 2;           // 0..63
  const int q = threadIdx.x & 3;            // quarter: r-base q*16
  bf16_t* orow = out + (size_t)(c0 + c) * ldout + r0 + q * 16;
#pragma unroll
  for (int half = 0; half < 2; ++half) {
    bf16x8 o;
#pragma unroll
    for (int j = 0; j < 8; ++j) o[j] = (__bf16)t[q * 16 + half * 8 + j][c];
    *reinterpret_cast<bf16x8*>(orow + half * 8) = o;
  }
}

// Fused RoPE for Q (pre-scaled by SC_Q) and K. One block per s; vectorized.
#define SC_Q 0.18033688f  // (1/sqrt(64)) * log2(e) -- softmax runs in exp2 domain

__global__ __launch_bounds__(256) void rope_kernel(const float* __restrict__ qkv,
    const float* __restrict__ cosT, const float* __restrict__ sinT,
    bf16_t* __restrict__ Qb, bf16_t* __restrict__ Kb) {
  const int s = blockIdx.x;
  const int tid = threadIdx.x;
  const int ch = tid & 15;  // chunk: elems ch*8..ch*8+7, pairs ch*4..ch*4+3
  float4 cs = *reinterpret_cast<const float4*>(cosT + s * 64 + ch * 4);
  float4 sn = *reinterpret_cast<const float4*>(sinT + s * 64 + ch * 4);
  {
    const int hq = tid >> 4;
    const float* src = qkv + (size_t)s * 3072 + hq * 128 + ch * 8;
    float4 a = *reinterpret_cast<const float4*>(src);
    float4 b = *reinterpret_cast<const float4*>(src + 4);
    bf16x8 o;
    o[0] = (__bf16)((a.x * cs.x - a.y * sn.x) * SC_Q);
    o[1] = (__bf16)((a.x * sn.x + a.y * cs.x) * SC_Q);
    o[2] = (__bf16)((a.z * cs.y - a.w * sn.y) * SC_Q);
    o[3] = (__bf16)((a.z * sn.y + a.w * cs.y) * SC_Q);
    o[4] = (__bf16)((b.x * cs.z - b.y * sn.z) * SC_Q);
    o[5] = (__bf16)((b.x * sn.z + b.y * cs.z) * SC_Q);
    o[6] = (__bf16)((b.z * cs.w - b.w * sn.w) * SC_Q);
    o[7] = (__bf16)((b.z * sn.w + b.w * cs.w) * SC_Q);
    *reinterpret_cast<bf16x8*>(Qb + ((size_t)hq * S_LEN + s) * HD_ + ch * 8) = o;
  }
  if (tid < 64) {
    const int kh = tid >> 4;
    const float* src = qkv + (size_t)s * 3072 + 2048 + kh * 128 + ch * 8;
    float4 a = *reinterpret_cast<const float4*>(src);
    float4 b = *reinterpret_cast<const float4*>(src + 4);
    bf16x8 o;
    o[0] = (__bf16)(a.x * cs.x - a.y * sn.x);
    o[1] = (__bf16)(a.x * sn.x + a.y * cs.x);
    o[2] = (__bf16)(a.z * cs.y - a.w * sn.y);
    o[3] = (__bf16)(a.z * sn.y + a.w * cs.y);
    o[4] = (__bf16)(b.x * cs.z - b.y * sn.z);
    o[5] = (__bf16)(b.x * sn.z + b.y * cs.z);
    o[6] = (__bf16)(b.z * cs.w - b.w * sn.w);
    o[7] = (__bf16)(b.z * sn.w + b.w * cs.w);
    *reinterpret_cast<bf16x8*>(Kb + ((size_t)kh * S_LEN + s) * HD_ + ch * 8) = o;
  }
}

// ---------------------------------------------------------------- GEMM (m97 structure)
// A: MxK bf16 row-major.  B: NxK bf16 (i.e. W^T).  C: MxN fp32.
#define BM 128
#define BN 128
#define BK 64

__global__ __launch_bounds__(256) void gemm_bf16_kernel(const bf16_t* __restrict__ A,
    const bf16_t* __restrict__ B, float* __restrict__ C, int M, int N, int K) {
  __shared__ __attribute__((aligned(16))) bf16_t aL[BM * BK];
  __shared__ __attribute__((aligned(16))) bf16_t bL[BN * BK];
  const int tid = threadIdx.x;
  const int wave = tid >> 6, lane = tid & 63;
  const int wr = wave >> 1, wc = wave & 1;
  const int l15 = lane & 15, l4 = lane >> 4;
  const int bm = blockIdx.y * BM, bn = blockIdx.x * BN;

  f32x4 zero = {0.f, 0.f, 0.f, 0.f};
  f32x4 acc[4][4];
#pragma unroll
  for (int m = 0; m < 4; ++m)
#pragma unroll
    for (int n = 0; n < 4; ++n) acc[m][n] = zero;

  const bf16_t* aSrc[4];
  const bf16_t* bSrc[4];
  bf16_t* aDst[4];
  bf16_t* bDst[4];
#pragma unroll
  for (int i = 0; i < 4; ++i) {
    int ci = i * 256 + tid;
    int r = ci >> 3;
    int cl = (ci & 7) ^ (r & 7);
    aSrc[i] = A + (size_t)(bm + r) * K + cl * 8;
    bSrc[i] = B + (size_t)(bn + r) * K + cl * 8;
    aDst[i] = aL + (i * 256 + wave * 64) * 8;
    bDst[i] = bL + (i * 256 + wave * 64) * 8;
  }

  for (int kt = 0; kt < K; kt += BK) {
#pragma unroll
    for (int i = 0; i < 4; ++i) gload_lds16(aSrc[i] + kt, aDst[i]);
#pragma unroll
    for (int i = 0; i < 4; ++i) gload_lds16(bSrc[i] + kt, bDst[i]);
    __syncthreads();
#pragma unroll
    for (int t = 0; t < 2; ++t) {
      bf16x8 af[4], bfr[4];
#pragma unroll
      for (int f = 0; f < 4; ++f) {
        int Ra = wr * 64 + f * 16 + l15;
        int ca = (t * 4 + l4) ^ (Ra & 7);
        af[f] = *reinterpret_cast<const bf16x8*>(aL + Ra * 64 + ca * 8);
        int Rb = wc * 64 + f * 16 + l15;
        int cb = (t * 4 + l4) ^ (Rb & 7);
        bfr[f] = *reinterpret_cast<const bf16x8*>(bL + Rb * 64 + cb * 8);
      }
#pragma unroll
      for (int m = 0; m < 4; ++m)
#pragma unroll
        for (int n = 0; n < 4; ++n) acc[m][n] = MFMA16(af[m], bfr[n], acc[m][n]);
    }
    __syncthreads();
  }

#pragma unroll
  for (int m = 0; m < 4; ++m) {
    int row0 = bm + wr * 64 + m * 16 + l4 * 4;
#pragma unroll
    for (int n = 0; n < 4; ++n) {
      int col = bn + wc * 64 + n * 16 + l15;
#pragma unroll
      for (int r = 0; r < 4; ++r) C[(size_t)(row0 + r) * N + col] = acc[m][n][r];
    }
  }
}

// ---------------------------------------------------------------- differential flash attention
// Swapped-operand: S^T = mfma(K, Q), q = lane (col), kv = regs. Q pre-scaled by SC_Q.
// Grid: (16 heads, 32 y). jt(y) = y<16 ? 31-y : y-16 — co-resident pairs (y, y+16)
// then sum to exactly 33 KV-tile iterations per CU (blocks b and b+256 share a CU
// under round-robin XCD dispatch), heavy blocks first in dispatch order.
// Block: 4 waves x 16 q-rows, KV tiles of 64, K/V double-buffered with prefetch.
// LDS = exactly 80 KiB -> 2 blocks/CU.
__global__ __launch_bounds__(256) void diff_attn_kernel(const bf16_t* __restrict__ Qb,
    const bf16_t* __restrict__ Kb, const bf16_t* __restrict__ VTb,
    const float* __restrict__ lambda_param, bf16_t* __restrict__ attn) {
  const int h = blockIdx.x;
  const int kvh = h >> 2;  // REP = 4
  const int jt = (blockIdx.y < 16) ? (31 - blockIdx.y) : (blockIdx.y - 16);
  const int tid = threadIdx.x, wave = tid >> 6, lane = tid & 63;
  const int l15 = lane & 15, l4 = lane >> 4;

  __shared__ __attribute__((aligned(16))) bf16_t kB[2][64 * 128];      // 32 KiB
  __shared__ __attribute__((aligned(16))) bf16_t vB[2][64 * 128];      // 32 KiB
  __shared__ __attribute__((aligned(16))) bf16_t pS[4][2][16 * 64];    // 16 KiB, XOR-swizzled

  const bf16_t* kBase = Kb + (size_t)kvh * S_LEN * HD_;
  const bf16_t* vBase = VTb + (size_t)kvh * HD_ * S_LEN;
  int kOff[4], vOff[4], dOff[4];
#pragma unroll
  for (int i = 0; i < 4; ++i) {
    int ci = i * 256 + tid;
    int kr = ci >> 4;
    kOff[i] = kr * HD_ + (((ci & 15) ^ (kr & 7)) * 8);
    int vr = ci >> 3;
    vOff[i] = vr * S_LEN + (((ci & 7) ^ (vr & 7)) * 8);
    dOff[i] = (i * 256 + wave * 64) * 8;
  }

  const float lam = 1.f / (1.f + __expf(-lambda_param[h]));
  const f32x4 zero = {0.f, 0.f, 0.f, 0.f};

  const int q0 = jt * 64;
  const int qg = q0 + wave * 16 + l15;  // this lane's q row (col of S^T)

  // Q fragments (B-operand: col=l15=q, k=hd). f=0,1 -> hd 0..63; f=2,3 -> hd 64..127
  const bf16_t* qp = Qb + ((size_t)h * S_LEN + qg) * HD_;
  bf16x8 qf[4];
#pragma unroll
  for (int f = 0; f < 4; ++f) qf[f] = *reinterpret_cast<const bf16x8*>(qp + f * 32 + l4 * 8);

  f32x4 o1[8], o2[8];
#pragma unroll
  for (int n = 0; n < 8; ++n) { o1[n] = zero; o2[n] = zero; }
  float m1 = -__builtin_inff(), m2 = -__builtin_inff(), l1 = 0.f, l2 = 0.f;

  // prologue: stage tile 0
#pragma unroll
  for (int i = 0; i < 4; ++i) gload_lds16(kBase + kOff[i], &kB[0][0] + dOff[i]);
#pragma unroll
  for (int i = 0; i < 4; ++i) gload_lds16(vBase + vOff[i], &vB[0][0] + dOff[i]);
  __syncthreads();

  for (int t = 0; t <= jt; ++t) {
    const int cur = t & 1;
    if (t < jt) {  // prefetch next tile (overlaps with compute)
      const size_t kv0n = (size_t)(t + 1) * 64;
#pragma unroll
      for (int i = 0; i < 4; ++i) gload_lds16(kBase + kv0n * HD_ + kOff[i], &kB[cur ^ 1][0] + dOff[i]);
#pragma unroll
      for (int i = 0; i < 4; ++i) gload_lds16(vBase + kv0n + vOff[i], &vB[cur ^ 1][0] + dOff[i]);
    }
    const bf16_t* kL = &kB[cur][0];
    const bf16_t* vL = &vB[cur][0];
    const int kv0 = t * 64;

    // S^T = K·Q^T (scores pre-scaled via Q)
    f32x4 s1[4], s2[4];
#pragma unroll
    for (int n = 0; n < 4; ++n) { s1[n] = zero; s2[n] = zero; }
#pragma unroll
    for (int tt = 0; tt < 2; ++tt) {
#pragma unroll
      for (int n = 0; n < 4; ++n) {
        const int Rk = n * 16 + l15;
        bf16x8 kf1 = *reinterpret_cast<const bf16x8*>(kL + Rk * 128 + (((tt * 4 + l4) ^ (Rk & 7)) * 8));
        s1[n] = MFMA16(kf1, qf[tt], s1[n]);
      }
    }
#pragma unroll
    for (int tt = 0; tt < 2; ++tt) {
#pragma unroll
      for (int n = 0; n < 4; ++n) {
        const int Rk = n * 16 + l15;
        bf16x8 kf2 = *reinterpret_cast<const bf16x8*>(kL + Rk * 128 + (((8 + tt * 4 + l4) ^ (Rk & 7)) * 8));
        s2[n] = MFMA16(kf2, qf[2 + tt], s2[n]);
      }
    }

    // causal mask only on the diagonal tile (wave-uniform branch)
    if (t == jt) {
#pragma unroll
      for (int n = 0; n < 4; ++n)
#pragma unroll
        for (int r = 0; r < 4; ++r)
          if (kv0 + n * 16 + l4 * 4 + r > qg) { s1[n][r] = -1e30f; s2[n][r] = -1e30f; }
    }

    // ---- online softmax (exp2 domain), T13 defer-rescale, half 1
    {
      float tmax = s1[0][0];
#pragma unroll
      for (int n = 0; n < 4; ++n)
#pragma unroll
        for (int r = 0; r < 4; ++r) tmax = fmaxf(tmax, s1[n][r]);
      tmax = fmaxf(tmax, __shfl_xor(tmax, 16));
      tmax = fmaxf(tmax, __shfl_xor(tmax, 32));
      if (!__all(tmax <= m1 + 8.f)) {
        const float mn = fmaxf(m1, tmax);
        const float sc = __builtin_exp2f(m1 - mn);
        m1 = mn;
        l1 *= sc;
#pragma unroll
        for (int n = 0; n < 8; ++n) o1[n] *= sc;
      }
      float rs = 0.f;
#pragma unroll
      for (int n = 0; n < 4; ++n) {
        float e0 = __builtin_exp2f(s1[n][0] - m1);
        float e1 = __builtin_exp2f(s1[n][1] - m1);
        float e2 = __builtin_exp2f(s1[n][2] - m1);
        float e3 = __builtin_exp2f(s1[n][3] - m1);
        rs += (e0 + e1) + (e2 + e3);
        // P^T store: row q=l15 (64 kv elems), logical chunk c = n*2 + (l4>>1), XOR (l15&7)
        int cswz = (n * 2 + (l4 >> 1)) ^ (l15 & 7);
        bf16x4 pk = {(__bf16)e0, (__bf16)e1, (__bf16)e2, (__bf16)e3};
        *reinterpret_cast<bf16x4*>(&pS[wave][0][l15 * 64 + cswz * 8 + (l4 & 1) * 4]) = pk;
      }
      rs += __shfl_xor(rs, 16);
      rs += __shfl_xor(rs, 32);
      l1 += rs;
    }
    // ---- half 2
    {
      float tmax = s2[0][0];
#pragma unroll
      for (int n = 0; n < 4; ++n)
#pragma unroll
        for (int r = 0; r < 4; ++r) tmax = fmaxf(tmax, s2[n][r]);
      tmax = fmaxf(tmax, __shfl_xor(tmax, 16));
      tmax = fmaxf(tmax, __shfl_xor(tmax, 32));
      if (!__all(tmax <= m2 + 8.f)) {
        const float mn = fmaxf(m2, tmax);
        const float sc = __builtin_exp2f(m2 - mn);
        m2 = mn;
        l2 *= sc;
#pragma unroll
        for (int n = 0; n < 8; ++n) o2[n] *= sc;
      }
      float rs = 0.f;
#pragma unroll
      for (int n = 0; n < 4; ++n) {
        float e0 = __builtin_exp2f(s2[n][0] - m2);
        float e1 = __builtin_exp2f(s2[n][1] - m2);
        float e2 = __builtin_exp2f(s2[n][2] - m2);
        float e3 = __builtin_exp2f(s2[n][3] - m2);
        rs += (e0 + e1) + (e2 + e3);
        int cswz = (n * 2 + (l4 >> 1)) ^ (l15 & 7);
        bf16x4 pk = {(__bf16)e0, (__bf16)e1, (__bf16)e2, (__bf16)e3};
        *reinterpret_cast<bf16x4*>(&pS[wave][1][l15 * 64 + cswz * 8 + (l4 & 1) * 4]) = pk;
      }
      rs += __shfl_xor(rs, 16);
      rs += __shfl_xor(rs, 32);
      l2 += rs;
    }

    // PV: O^T += V^T · P^T.  A = V^T (rows=d), B = P^T (cols=q, k=kv from pS).
#pragma unroll
    for (int kt = 0; kt < 2; ++kt) {
      int cp = ((kt * 4 + l4) ^ (l15 & 7)) * 8;
      bf16x8 pf1 = *reinterpret_cast<const bf16x8*>(&pS[wave][0][l15 * 64 + cp]);
      bf16x8 pf2 = *reinterpret_cast<const bf16x8*>(&pS[wave][1][l15 * 64 + cp]);
#pragma unroll
      for (int n = 0; n < 8; ++n) {
        const int Rv = n * 16 + l15;
        bf16x8 vf = *reinterpret_cast<const bf16x8*>(vL + Rv * 64 + (((kt * 4 + l4) ^ (Rv & 7)) * 8));
        o1[n] = MFMA16(vf, pf1, o1[n]);
        o2[n] = MFMA16(vf, pf2, o2[n]);
      }
    }
    __syncthreads();
  }

  // epilogue: O^T[d][q]: lane q=qg, d = n*16 + l4*4 + r
  const float i1 = 1.f / l1, i2 = lam / l2;
  bf16_t* orow = attn + (size_t)qg * D_MODEL + h * HD_;
#pragma unroll
  for (int n = 0; n < 8; ++n) {
    bf16x4 w = {(__bf16)((o1[n][0] * i1 - o2[n][0] * i2) * 0.5f),
                (__bf16)((o1[n][1] * i1 - o2[n][1] * i2) * 0.5f),
                (__bf16)((o1[n][2] * i1 - o2[n][2] * i2) * 0.5f),
                (__bf16)((o1[n][3] * i1 - o2[n][3] * i2) * 0.5f)};
    *reinterpret_cast<bf16x4*>(orow + n * 16 + l4 * 4) = w;
  }
}

// ---------------------------------------------------------------- launch
extern "C" void kernel_launch(void* const* d_in, const int* in_sizes, int n_in,
                              void* d_out, int out_size, void* d_ws, size_t ws_size,
                              hipStream_t stream) {
  const float* x    = (const float*)d_in[0];
  const float* fcos = (const float*)d_in[1];
  const float* fsin = (const float*)d_in[2];
  const float* Wq   = (const float*)d_in[3];
  const float* Wk   = (const float*)d_in[4];
  const float* Wv   = (const float*)d_in[5];
  const float* Wo   = (const float*)d_in[6];
  const float* lam  = (const float*)d_in[7];
  float* out = (float*)d_out;

  // workspace layout (52 MB total, phases overlap dead regions):
  //  [0,8)   xb  -> attnb      [8,20) WqkvT -> Qb/Kb/VT      [20,28) WoT      [28,52) QKV fp32
  char* w = (char*)d_ws;
  bf16_t* xb    = (bf16_t*)(w);
  bf16_t* attnb = (bf16_t*)(w);
  bf16_t* WqkvT = (bf16_t*)(w + (8ull << 20));
  bf16_t* Qb    = (bf16_t*)(w + (8ull << 20));
  bf16_t* Kb    = (bf16_t*)(w + (16ull << 20));
  bf16_t* VT    = (bf16_t*)(w + (18ull << 20));
  bf16_t* WoT   = (bf16_t*)(w + (20ull << 20));
  float*  QKV   = (float*) (w + (28ull << 20));

  cast_x_kernel<<<2048, 256, 0, stream>>>(x, xb, 524288);
  transpose_cast64_kernel<<<dim3(32, 32), 256, 0, stream>>>(Wq, WqkvT, 2048, 2048);
  transpose_cast64_kernel<<<dim3(8, 32), 256, 0, stream>>>(Wk, WqkvT + 2048 * 2048, 512, 2048);
  transpose_cast64_kernel<<<dim3(8, 32), 256, 0, stream>>>(Wv, WqkvT + 2560 * 2048, 512, 2048);
  transpose_cast64_kernel<<<dim3(32, 32), 256, 0, stream>>>(Wo, WoT, 2048, 2048);

  gemm_bf16_kernel<<<dim3(24, 16), 256, 0, stream>>>(xb, WqkvT, QKV, 2048, 3072, 2048);

  rope_kernel<<<2048, 256, 0, stream>>>(QKV, fcos, fsin, Qb, Kb);
  transpose_cast64_kernel<<<dim3(8, 32), 256, 0, stream>>>(QKV + 2560, VT, 3072, 2048);

  diff_attn_kernel<<<dim3(16, 32), 256, 0, stream>>>(Qb, Kb, VT, lam, attnb);

  gemm_bf16_kernel<<<dim3(16, 16), 256, 0, stream>>>(attnb, WoT, out, 2048, 2048, 2048);
}

// Round 9
// 286.513 us; speedup vs baseline: 1.0713x; 1.0713x over previous
//
#include <hip/hip_runtime.h>
#include <hip/hip_bf16.h>
#include <cstdint>

typedef __bf16 bf16_t;
typedef __attribute__((ext_vector_type(8))) __bf16 bf16x8;
typedef __attribute__((ext_vector_type(4))) __bf16 bf16x4;
typedef __attribute__((ext_vector_type(4))) float f32x4;

#define S_LEN 2048
#define D_MODEL 2048
#define NH 16
#define NKV 4
#define HD_ 128

#define MFMA16(a, b, c) __builtin_amdgcn_mfma_f32_16x16x32_bf16((a), (b), (c), 0, 0, 0)

// Async global->LDS, 16B per lane. LDS dest must be WAVE-UNIFORM base; HW adds lane*16.
__device__ __forceinline__ void gload_lds16(const void* g, void* l) {
  __builtin_amdgcn_global_load_lds((__attribute__((address_space(1))) void*)((void*)g),
                                   (__attribute__((address_space(3))) void*)(l), 16, 0, 0);
}

// ---------------------------------------------------------------- prep kernels
__global__ __launch_bounds__(256) void cast_x_kernel(const float* __restrict__ in,
                                                     bf16_t* __restrict__ out, int n8) {
  int i = blockIdx.x * 256 + threadIdx.x;
  if (i >= n8) return;
  float4 a = reinterpret_cast<const float4*>(in)[2 * i];
  float4 b = reinterpret_cast<const float4*>(in)[2 * i + 1];
  bf16x8 o = {(__bf16)a.x, (__bf16)a.y, (__bf16)a.z, (__bf16)a.w,
              (__bf16)b.x, (__bf16)b.y, (__bf16)b.z, (__bf16)b.w};
  *reinterpret_cast<bf16x8*>(out + (size_t)i * 8) = o;
}

// in: [R][C] fp32 (ld=ldin) -> out: [C][R] bf16 (ld=ldout). 64x64 tile, 256 threads.
__global__ __launch_bounds__(256) void transpose_cast64_kernel(const float* __restrict__ in,
    bf16_t* __restrict__ out, int ldin, int ldout) {
  __shared__ float t[64][65];
  const int c0 = blockIdx.x * 64, r0 = blockIdx.y * 64;
  const int rr = threadIdx.x >> 4;          // 0..15
  const int cc = (threadIdx.x & 15) * 4;    // 0..60
#pragma unroll
  for (int p = 0; p < 4; ++p) {
    int r = rr + p * 16;
    float4 v = *reinterpret_cast<const float4*>(in + (size_t)(r0 + r) * ldin + c0 + cc);
    t[r][cc] = v.x; t[r][cc + 1] = v.y; t[r][cc + 2] = v.z; t[r][cc + 3] = v.w;
  }
  __syncthreads();
  const int c = threadIdx.x >> 2;           // 0..63
  const int q = threadIdx.x & 3;            // quarter: r-base q*16
  bf16_t* orow = out + (size_t)(c0 + c) * ldout + r0 + q * 16;
#pragma unroll
  for (int half = 0; half < 2; ++half) {
    bf16x8 o;
#pragma unroll
    for (int j = 0; j < 8; ++j) o[j] = (__bf16)t[q * 16 + half * 8 + j][c];
    *reinterpret_cast<bf16x8*>(orow + half * 8) = o;
  }
}

// Fused RoPE for Q (pre-scaled by SC_Q) and K. One block per s; vectorized.
#define SC_Q 0.18033688f  // (1/sqrt(64)) * log2(e) -- softmax runs in exp2 domain

__global__ __launch_bounds__(256) void rope_kernel(const float* __restrict__ qkv,
    const float* __restrict__ cosT, const float* __restrict__ sinT,
    bf16_t* __restrict__ Qb, bf16_t* __restrict__ Kb) {
  const int s = blockIdx.x;
  const int tid = threadIdx.x;
  const int ch = tid & 15;  // chunk: elems ch*8..ch*8+7, pairs ch*4..ch*4+3
  float4 cs = *reinterpret_cast<const float4*>(cosT + s * 64 + ch * 4);
  float4 sn = *reinterpret_cast<const float4*>(sinT + s * 64 + ch * 4);
  {
    const int hq = tid >> 4;
    const float* src = qkv + (size_t)s * 3072 + hq * 128 + ch * 8;
    float4 a = *reinterpret_cast<const float4*>(src);
    float4 b = *reinterpret_cast<const float4*>(src + 4);
    bf16x8 o;
    o[0] = (__bf16)((a.x * cs.x - a.y * sn.x) * SC_Q);
    o[1] = (__bf16)((a.x * sn.x + a.y * cs.x) * SC_Q);
    o[2] = (__bf16)((a.z * cs.y - a.w * sn.y) * SC_Q);
    o[3] = (__bf16)((a.z * sn.y + a.w * cs.y) * SC_Q);
    o[4] = (__bf16)((b.x * cs.z - b.y * sn.z) * SC_Q);
    o[5] = (__bf16)((b.x * sn.z + b.y * cs.z) * SC_Q);
    o[6] = (__bf16)((b.z * cs.w - b.w * sn.w) * SC_Q);
    o[7] = (__bf16)((b.z * sn.w + b.w * cs.w) * SC_Q);
    *reinterpret_cast<bf16x8*>(Qb + ((size_t)hq * S_LEN + s) * HD_ + ch * 8) = o;
  }
  if (tid < 64) {
    const int kh = tid >> 4;
    const float* src = qkv + (size_t)s * 3072 + 2048 + kh * 128 + ch * 8;
    float4 a = *reinterpret_cast<const float4*>(src);
    float4 b = *reinterpret_cast<const float4*>(src + 4);
    bf16x8 o;
    o[0] = (__bf16)(a.x * cs.x - a.y * sn.x);
    o[1] = (__bf16)(a.x * sn.x + a.y * cs.x);
    o[2] = (__bf16)(a.z * cs.y - a.w * sn.y);
    o[3] = (__bf16)(a.z * sn.y + a.w * cs.y);
    o[4] = (__bf16)(b.x * cs.z - b.y * sn.z);
    o[5] = (__bf16)(b.x * sn.z + b.y * cs.z);
    o[6] = (__bf16)(b.z * cs.w - b.w * sn.w);
    o[7] = (__bf16)(b.z * sn.w + b.w * cs.w);
    *reinterpret_cast<bf16x8*>(Kb + ((size_t)kh * S_LEN + s) * HD_ + ch * 8) = o;
  }
}

// ---------------------------------------------------------------- GEMM, 128xBNv tile
// A: MxK bf16 row-major.  B: NxK bf16 (W^T).  C: MxN fp32.
// BNv=64: 24 KiB LDS, grid 2x blocks vs 128^2 -> ~3 blocks/CU at N~2048 (TLP for latency).
#define BM 128
#define BK 64

template <int BNv>
__global__ __launch_bounds__(256) void gemm_bf16_kernel(const bf16_t* __restrict__ A,
    const bf16_t* __restrict__ B, float* __restrict__ C, int M, int N, int K) {
  constexpr int NF = BNv / 32;             // N-frags per wave
  constexpr int BITER = BNv * 8 / 256;     // B-staging chunks per thread
  __shared__ __attribute__((aligned(16))) bf16_t aL[BM * BK];
  __shared__ __attribute__((aligned(16))) bf16_t bL[BNv * BK];
  const int tid = threadIdx.x;
  const int wave = tid >> 6, lane = tid & 63;
  const int wr = wave >> 1, wc = wave & 1;
  const int l15 = lane & 15, l4 = lane >> 4;
  const int bm = blockIdx.y * BM, bn = blockIdx.x * BNv;

  f32x4 zero = {0.f, 0.f, 0.f, 0.f};
  f32x4 acc[4][NF];
#pragma unroll
  for (int m = 0; m < 4; ++m)
#pragma unroll
    for (int n = 0; n < NF; ++n) acc[m][n] = zero;

  const bf16_t* aSrc[4];
  bf16_t* aDst[4];
#pragma unroll
  for (int i = 0; i < 4; ++i) {
    int ci = i * 256 + tid;
    int r = ci >> 3;
    int cl = (ci & 7) ^ (r & 7);
    aSrc[i] = A + (size_t)(bm + r) * K + cl * 8;
    aDst[i] = aL + (i * 256 + wave * 64) * 8;
  }
  const bf16_t* bSrc[BITER];
  bf16_t* bDst[BITER];
#pragma unroll
  for (int i = 0; i < BITER; ++i) {
    int ci = i * 256 + tid;
    int r = ci >> 3;
    int cl = (ci & 7) ^ (r & 7);
    bSrc[i] = B + (size_t)(bn + r) * K + cl * 8;
    bDst[i] = bL + (i * 256 + wave * 64) * 8;
  }

  for (int kt = 0; kt < K; kt += BK) {
#pragma unroll
    for (int i = 0; i < 4; ++i) gload_lds16(aSrc[i] + kt, aDst[i]);
#pragma unroll
    for (int i = 0; i < BITER; ++i) gload_lds16(bSrc[i] + kt, bDst[i]);
    __syncthreads();
#pragma unroll
    for (int t = 0; t < 2; ++t) {
      bf16x8 af[4], bfr[NF];
#pragma unroll
      for (int f = 0; f < 4; ++f) {
        int Ra = wr * 64 + f * 16 + l15;
        int ca = (t * 4 + l4) ^ (Ra & 7);
        af[f] = *reinterpret_cast<const bf16x8*>(aL + Ra * 64 + ca * 8);
      }
#pragma unroll
      for (int f = 0; f < NF; ++f) {
        int Rb = wc * (BNv / 2) + f * 16 + l15;
        int cb = (t * 4 + l4) ^ (Rb & 7);
        bfr[f] = *reinterpret_cast<const bf16x8*>(bL + Rb * 64 + cb * 8);
      }
      __builtin_amdgcn_s_setprio(1);
#pragma unroll
      for (int m = 0; m < 4; ++m)
#pragma unroll
        for (int n = 0; n < NF; ++n) acc[m][n] = MFMA16(af[m], bfr[n], acc[m][n]);
      __builtin_amdgcn_s_setprio(0);
    }
    __syncthreads();
  }

#pragma unroll
  for (int m = 0; m < 4; ++m) {
    int row0 = bm + wr * 64 + m * 16 + l4 * 4;
#pragma unroll
    for (int n = 0; n < NF; ++n) {
      int col = bn + wc * (BNv / 2) + n * 16 + l15;
#pragma unroll
      for (int r = 0; r < 4; ++r) C[(size_t)(row0 + r) * N + col] = acc[m][n][r];
    }
  }
}

// ---------------------------------------------------------------- differential flash attention
// Swapped-operand: S^T = mfma(K, Q), q = lane (col), kv = regs. Q pre-scaled by SC_Q.
// FLAT grid of 512 blocks; consecutive blocks (2p, 2p+1) -> (jt=31-t, jt=t), t=p&15,
// h=p>>4. Measured dispatch fills a CU's two 80KiB slots with CONSECUTIVE blocks
// (R5/R7 counters), so each CU's pair sums to exactly 33 KV-tile iterations.
// Block: 4 waves x 16 q-rows, KV tiles of 64, K/V double-buffered with prefetch.
__global__ __launch_bounds__(256) void diff_attn_kernel(const bf16_t* __restrict__ Qb,
    const bf16_t* __restrict__ Kb, const bf16_t* __restrict__ VTb,
    const float* __restrict__ lambda_param, bf16_t* __restrict__ attn) {
  const int b = blockIdx.x;
  const int p = b >> 1;
  const int h = p >> 4;
  const int tdx = p & 15;
  const int jt = (b & 1) ? tdx : (31 - tdx);  // heavy first within pair
  const int kvh = h >> 2;  // REP = 4
  const int tid = threadIdx.x, wave = tid >> 6, lane = tid & 63;
  const int l15 = lane & 15, l4 = lane >> 4;

  __shared__ __attribute__((aligned(16))) bf16_t kB[2][64 * 128];      // 32 KiB
  __shared__ __attribute__((aligned(16))) bf16_t vB[2][64 * 128];      // 32 KiB
  __shared__ __attribute__((aligned(16))) bf16_t pS[4][2][16 * 64];    // 16 KiB

  const bf16_t* kBase = Kb + (size_t)kvh * S_LEN * HD_;
  const bf16_t* vBase = VTb + (size_t)kvh * HD_ * S_LEN;
  int kOff[4], vOff[4], dOff[4];
#pragma unroll
  for (int i = 0; i < 4; ++i) {
    int ci = i * 256 + tid;
    int kr = ci >> 4;
    kOff[i] = kr * HD_ + (((ci & 15) ^ (kr & 7)) * 8);
    int vr = ci >> 3;
    vOff[i] = vr * S_LEN + (((ci & 7) ^ (vr & 7)) * 8);
    dOff[i] = (i * 256 + wave * 64) * 8;
  }

  const float lam = 1.f / (1.f + __expf(-lambda_param[h]));
  const f32x4 zero = {0.f, 0.f, 0.f, 0.f};

  const int q0 = jt * 64;
  const int qg = q0 + wave * 16 + l15;  // this lane's q row (col of S^T)

  const bf16_t* qp = Qb + ((size_t)h * S_LEN + qg) * HD_;
  bf16x8 qf[4];
#pragma unroll
  for (int f = 0; f < 4; ++f) qf[f] = *reinterpret_cast<const bf16x8*>(qp + f * 32 + l4 * 8);

  f32x4 o1[8], o2[8];
#pragma unroll
  for (int n = 0; n < 8; ++n) { o1[n] = zero; o2[n] = zero; }
  float m1 = -__builtin_inff(), m2 = -__builtin_inff(), l1 = 0.f, l2 = 0.f;

  // prologue: stage tile 0
#pragma unroll
  for (int i = 0; i < 4; ++i) gload_lds16(kBase + kOff[i], &kB[0][0] + dOff[i]);
#pragma unroll
  for (int i = 0; i < 4; ++i) gload_lds16(vBase + vOff[i], &vB[0][0] + dOff[i]);
  __syncthreads();

  for (int t = 0; t <= jt; ++t) {
    const int cur = t & 1;
    if (t < jt) {  // prefetch next tile (overlaps with compute)
      const size_t kv0n = (size_t)(t + 1) * 64;
#pragma unroll
      for (int i = 0; i < 4; ++i) gload_lds16(kBase + kv0n * HD_ + kOff[i], &kB[cur ^ 1][0] + dOff[i]);
#pragma unroll
      for (int i = 0; i < 4; ++i) gload_lds16(vBase + kv0n + vOff[i], &vB[cur ^ 1][0] + dOff[i]);
    }
    const bf16_t* kL = &kB[cur][0];
    const bf16_t* vL = &vB[cur][0];
    const int kv0 = t * 64;

    // S^T = K·Q^T (scores pre-scaled via Q)
    f32x4 s1[4], s2[4];
#pragma unroll
    for (int n = 0; n < 4; ++n) { s1[n] = zero; s2[n] = zero; }
    __builtin_amdgcn_s_setprio(1);
#pragma unroll
    for (int tt = 0; tt < 2; ++tt) {
#pragma unroll
      for (int n = 0; n < 4; ++n) {
        const int Rk = n * 16 + l15;
        bf16x8 kf1 = *reinterpret_cast<const bf16x8*>(kL + Rk * 128 + (((tt * 4 + l4) ^ (Rk & 7)) * 8));
        s1[n] = MFMA16(kf1, qf[tt], s1[n]);
      }
    }
#pragma unroll
    for (int tt = 0; tt < 2; ++tt) {
#pragma unroll
      for (int n = 0; n < 4; ++n) {
        const int Rk = n * 16 + l15;
        bf16x8 kf2 = *reinterpret_cast<const bf16x8*>(kL + Rk * 128 + (((8 + tt * 4 + l4) ^ (Rk & 7)) * 8));
        s2[n] = MFMA16(kf2, qf[2 + tt], s2[n]);
      }
    }
    __builtin_amdgcn_s_setprio(0);

    // causal mask only on the diagonal tile (wave-uniform branch)
    if (t == jt) {
#pragma unroll
      for (int n = 0; n < 4; ++n)
#pragma unroll
        for (int r = 0; r < 4; ++r)
          if (kv0 + n * 16 + l4 * 4 + r > qg) { s1[n][r] = -1e30f; s2[n][r] = -1e30f; }
    }

    // ---- online softmax (exp2 domain), defer-rescale, half 1
    {
      float ma[4];
#pragma unroll
      for (int n = 0; n < 4; ++n)
        ma[n] = fmaxf(fmaxf(s1[n][0], s1[n][1]), fmaxf(s1[n][2], s1[n][3]));
      float tmax = fmaxf(fmaxf(ma[0], ma[1]), fmaxf(ma[2], ma[3]));
      tmax = fmaxf(tmax, __shfl_xor(tmax, 16));
      tmax = fmaxf(tmax, __shfl_xor(tmax, 32));
      if (!__all(tmax <= m1 + 8.f)) {
        const float mn = fmaxf(m1, tmax);
        const float sc = __builtin_exp2f(m1 - mn);
        m1 = mn;
        l1 *= sc;
#pragma unroll
        for (int n = 0; n < 8; ++n) o1[n] *= sc;
      }
      float rsn[4];
#pragma unroll
      for (int n = 0; n < 4; ++n) {
        float e0 = __builtin_exp2f(s1[n][0] - m1);
        float e1 = __builtin_exp2f(s1[n][1] - m1);
        float e2 = __builtin_exp2f(s1[n][2] - m1);
        float e3 = __builtin_exp2f(s1[n][3] - m1);
        rsn[n] = (e0 + e1) + (e2 + e3);
        int cswz = (n * 2 + (l4 >> 1)) ^ (l15 & 7);
        bf16x4 pk = {(__bf16)e0, (__bf16)e1, (__bf16)e2, (__bf16)e3};
        *reinterpret_cast<bf16x4*>(&pS[wave][0][l15 * 64 + cswz * 8 + (l4 & 1) * 4]) = pk;
      }
      float rs = (rsn[0] + rsn[1]) + (rsn[2] + rsn[3]);
      rs += __shfl_xor(rs, 16);
      rs += __shfl_xor(rs, 32);
      l1 += rs;
    }
    // ---- half 2
    {
      float ma[4];
#pragma unroll
      for (int n = 0; n < 4; ++n)
        ma[n] = fmaxf(fmaxf(s2[n][0], s2[n][1]), fmaxf(s2[n][2], s2[n][3]));
      float tmax = fmaxf(fmaxf(ma[0], ma[1]), fmaxf(ma[2], ma[3]));
      tmax = fmaxf(tmax, __shfl_xor(tmax, 16));
      tmax = fmaxf(tmax, __shfl_xor(tmax, 32));
      if (!__all(tmax <= m2 + 8.f)) {
        const float mn = fmaxf(m2, tmax);
        const float sc = __builtin_exp2f(m2 - mn);
        m2 = mn;
        l2 *= sc;
#pragma unroll
        for (int n = 0; n < 8; ++n) o2[n] *= sc;
      }
      float rsn[4];
#pragma unroll
      for (int n = 0; n < 4; ++n) {
        float e0 = __builtin_exp2f(s2[n][0] - m2);
        float e1 = __builtin_exp2f(s2[n][1] - m2);
        float e2 = __builtin_exp2f(s2[n][2] - m2);
        float e3 = __builtin_exp2f(s2[n][3] - m2);
        rsn[n] = (e0 + e1) + (e2 + e3);
        int cswz = (n * 2 + (l4 >> 1)) ^ (l15 & 7);
        bf16x4 pk = {(__bf16)e0, (__bf16)e1, (__bf16)e2, (__bf16)e3};
        *reinterpret_cast<bf16x4*>(&pS[wave][1][l15 * 64 + cswz * 8 + (l4 & 1) * 4]) = pk;
      }
      float rs = (rsn[0] + rsn[1]) + (rsn[2] + rsn[3]);
      rs += __shfl_xor(rs, 16);
      rs += __shfl_xor(rs, 32);
      l2 += rs;
    }

    // PV: O^T += V^T · P^T.
    __builtin_amdgcn_s_setprio(1);
#pragma unroll
    for (int kt = 0; kt < 2; ++kt) {
      int cp = ((kt * 4 + l4) ^ (l15 & 7)) * 8;
      bf16x8 pf1 = *reinterpret_cast<const bf16x8*>(&pS[wave][0][l15 * 64 + cp]);
      bf16x8 pf2 = *reinterpret_cast<const bf16x8*>(&pS[wave][1][l15 * 64 + cp]);
#pragma unroll
      for (int n = 0; n < 8; ++n) {
        const int Rv = n * 16 + l15;
        bf16x8 vf = *reinterpret_cast<const bf16x8*>(vL + Rv * 64 + (((kt * 4 + l4) ^ (Rv & 7)) * 8));
        o1[n] = MFMA16(vf, pf1, o1[n]);
        o2[n] = MFMA16(vf, pf2, o2[n]);
      }
    }
    __builtin_amdgcn_s_setprio(0);
    __syncthreads();
  }

  // epilogue: O^T[d][q]: lane q=qg, d = n*16 + l4*4 + r
  const float i1 = 1.f / l1, i2 = lam / l2;
  bf16_t* orow = attn + (size_t)qg * D_MODEL + h * HD_;
#pragma unroll
  for (int n = 0; n < 8; ++n) {
    bf16x4 w = {(__bf16)((o1[n][0] * i1 - o2[n][0] * i2) * 0.5f),
                (__bf16)((o1[n][1] * i1 - o2[n][1] * i2) * 0.5f),
                (__bf16)((o1[n][2] * i1 - o2[n][2] * i2) * 0.5f),
                (__bf16)((o1[n][3] * i1 - o2[n][3] * i2) * 0.5f)};
    *reinterpret_cast<bf16x4*>(orow + n * 16 + l4 * 4) = w;
  }
}

// ---------------------------------------------------------------- launch
extern "C" void kernel_launch(void* const* d_in, const int* in_sizes, int n_in,
                              void* d_out, int out_size, void* d_ws, size_t ws_size,
                              hipStream_t stream) {
  const float* x    = (const float*)d_in[0];
  const float* fcos = (const float*)d_in[1];
  const float* fsin = (const float*)d_in[2];
  const float* Wq   = (const float*)d_in[3];
  const float* Wk   = (const float*)d_in[4];
  const float* Wv   = (const float*)d_in[5];
  const float* Wo   = (const float*)d_in[6];
  const float* lam  = (const float*)d_in[7];
  float* out = (float*)d_out;

  // workspace layout (52 MB total, phases overlap dead regions):
  //  [0,8)   xb  -> attnb      [8,20) WqkvT -> Qb/Kb/VT      [20,28) WoT      [28,52) QKV fp32
  char* w = (char*)d_ws;
  bf16_t* xb    = (bf16_t*)(w);
  bf16_t* attnb = (bf16_t*)(w);
  bf16_t* WqkvT = (bf16_t*)(w + (8ull << 20));
  bf16_t* Qb    = (bf16_t*)(w + (8ull << 20));
  bf16_t* Kb    = (bf16_t*)(w + (16ull << 20));
  bf16_t* VT    = (bf16_t*)(w + (18ull << 20));
  bf16_t* WoT   = (bf16_t*)(w + (20ull << 20));
  float*  QKV   = (float*) (w + (28ull << 20));

  cast_x_kernel<<<2048, 256, 0, stream>>>(x, xb, 524288);
  transpose_cast64_kernel<<<dim3(32, 32), 256, 0, stream>>>(Wq, WqkvT, 2048, 2048);
  transpose_cast64_kernel<<<dim3(8, 32), 256, 0, stream>>>(Wk, WqkvT + 2048 * 2048, 512, 2048);
  transpose_cast64_kernel<<<dim3(8, 32), 256, 0, stream>>>(Wv, WqkvT + 2560 * 2048, 512, 2048);
  transpose_cast64_kernel<<<dim3(32, 32), 256, 0, stream>>>(Wo, WoT, 2048, 2048);

  gemm_bf16_kernel<64><<<dim3(48, 16), 256, 0, stream>>>(xb, WqkvT, QKV, 2048, 3072, 2048);

  rope_kernel<<<2048, 256, 0, stream>>>(QKV, fcos, fsin, Qb, Kb);
  transpose_cast64_kernel<<<dim3(8, 32), 256, 0, stream>>>(QKV + 2560, VT, 3072, 2048);

  diff_attn_kernel<<<512, 256, 0, stream>>>(Qb, Kb, VT, lam, attnb);

  gemm_bf16_kernel<64><<<dim3(32, 16), 256, 0, stream>>>(attnb, WoT, out, 2048, 2048, 2048);
}

// Round 10
// 278.714 us; speedup vs baseline: 1.1013x; 1.0280x over previous
//
#include <hip/hip_runtime.h>
#include <hip/hip_bf16.h>
#include <cstdint>

typedef __bf16 bf16_t;
typedef __attribute__((ext_vector_type(8))) __bf16 bf16x8;
typedef __attribute__((ext_vector_type(4))) __bf16 bf16x4;
typedef __attribute__((ext_vector_type(4))) float f32x4;

#define S_LEN 2048
#define D_MODEL 2048
#define NH 16
#define NKV 4
#define HD_ 128

#define MFMA16(a, b, c) __builtin_amdgcn_mfma_f32_16x16x32_bf16((a), (b), (c), 0, 0, 0)

// Async global->LDS, 16B per lane. LDS dest must be WAVE-UNIFORM base; HW adds lane*16.
__device__ __forceinline__ void gload_lds16(const void* g, void* l) {
  __builtin_amdgcn_global_load_lds((__attribute__((address_space(1))) void*)((void*)g),
                                   (__attribute__((address_space(3))) void*)(l), 16, 0, 0);
}

// ---------------------------------------------------------------- prep kernels
__global__ __launch_bounds__(256) void cast_x_kernel(const float* __restrict__ in,
                                                     bf16_t* __restrict__ out, int n8) {
  int i = blockIdx.x * 256 + threadIdx.x;
  if (i >= n8) return;
  float4 a = reinterpret_cast<const float4*>(in)[2 * i];
  float4 b = reinterpret_cast<const float4*>(in)[2 * i + 1];
  bf16x8 o = {(__bf16)a.x, (__bf16)a.y, (__bf16)a.z, (__bf16)a.w,
              (__bf16)b.x, (__bf16)b.y, (__bf16)b.z, (__bf16)b.w};
  *reinterpret_cast<bf16x8*>(out + (size_t)i * 8) = o;
}

// in: [R][C] fp32 (ld=ldin) -> out: [C][R] bf16 (ld=ldout). 64x64 tile, 256 threads.
__global__ __launch_bounds__(256) void transpose_cast64_kernel(const float* __restrict__ in,
    bf16_t* __restrict__ out, int ldin, int ldout) {
  __shared__ float t[64][65];
  const int c0 = blockIdx.x * 64, r0 = blockIdx.y * 64;
  const int rr = threadIdx.x >> 4;          // 0..15
  const int cc = (threadIdx.x & 15) * 4;    // 0..60
#pragma unroll
  for (int p = 0; p < 4; ++p) {
    int r = rr + p * 16;
    float4 v = *reinterpret_cast<const float4*>(in + (size_t)(r0 + r) * ldin + c0 + cc);
    t[r][cc] = v.x; t[r][cc + 1] = v.y; t[r][cc + 2] = v.z; t[r][cc + 3] = v.w;
  }
  __syncthreads();
  const int c = threadIdx.x >> 2;           // 0..63
  const int q = threadIdx.x & 3;            // quarter: r-base q*16
  bf16_t* orow = out + (size_t)(c0 + c) * ldout + r0 + q * 16;
#pragma unroll
  for (int half = 0; half < 2; ++half) {
    bf16x8 o;
#pragma unroll
    for (int j = 0; j < 8; ++j) o[j] = (__bf16)t[q * 16 + half * 8 + j][c];
    *reinterpret_cast<bf16x8*>(orow + half * 8) = o;
  }
}

// Fused RoPE for Q (pre-scaled by SC_Q) and K. One block per s; vectorized.
#define SC_Q 0.18033688f  // (1/sqrt(64)) * log2(e) -- softmax runs in exp2 domain

__global__ __launch_bounds__(256) void rope_kernel(const float* __restrict__ qkv,
    const float* __restrict__ cosT, const float* __restrict__ sinT,
    bf16_t* __restrict__ Qb, bf16_t* __restrict__ Kb) {
  const int s = blockIdx.x;
  const int tid = threadIdx.x;
  const int ch = tid & 15;  // chunk: elems ch*8..ch*8+7, pairs ch*4..ch*4+3
  float4 cs = *reinterpret_cast<const float4*>(cosT + s * 64 + ch * 4);
  float4 sn = *reinterpret_cast<const float4*>(sinT + s * 64 + ch * 4);
  {
    const int hq = tid >> 4;
    const float* src = qkv + (size_t)s * 3072 + hq * 128 + ch * 8;
    float4 a = *reinterpret_cast<const float4*>(src);
    float4 b = *reinterpret_cast<const float4*>(src + 4);
    bf16x8 o;
    o[0] = (__bf16)((a.x * cs.x - a.y * sn.x) * SC_Q);
    o[1] = (__bf16)((a.x * sn.x + a.y * cs.x) * SC_Q);
    o[2] = (__bf16)((a.z * cs.y - a.w * sn.y) * SC_Q);
    o[3] = (__bf16)((a.z * sn.y + a.w * cs.y) * SC_Q);
    o[4] = (__bf16)((b.x * cs.z - b.y * sn.z) * SC_Q);
    o[5] = (__bf16)((b.x * sn.z + b.y * cs.z) * SC_Q);
    o[6] = (__bf16)((b.z * cs.w - b.w * sn.w) * SC_Q);
    o[7] = (__bf16)((b.z * sn.w + b.w * cs.w) * SC_Q);
    *reinterpret_cast<bf16x8*>(Qb + ((size_t)hq * S_LEN + s) * HD_ + ch * 8) = o;
  }
  if (tid < 64) {
    const int kh = tid >> 4;
    const float* src = qkv + (size_t)s * 3072 + 2048 + kh * 128 + ch * 8;
    float4 a = *reinterpret_cast<const float4*>(src);
    float4 b = *reinterpret_cast<const float4*>(src + 4);
    bf16x8 o;
    o[0] = (__bf16)(a.x * cs.x - a.y * sn.x);
    o[1] = (__bf16)(a.x * sn.x + a.y * cs.x);
    o[2] = (__bf16)(a.z * cs.y - a.w * sn.y);
    o[3] = (__bf16)(a.z * sn.y + a.w * cs.y);
    o[4] = (__bf16)(b.x * cs.z - b.y * sn.z);
    o[5] = (__bf16)(b.x * sn.z + b.y * cs.z);
    o[6] = (__bf16)(b.z * cs.w - b.w * sn.w);
    o[7] = (__bf16)(b.z * sn.w + b.w * cs.w);
    *reinterpret_cast<bf16x8*>(Kb + ((size_t)kh * S_LEN + s) * HD_ + ch * 8) = o;
  }
}

// ---------------------------------------------------------------- GEMM, 128xBNv tile
// A: MxK bf16 row-major.  B: NxK bf16 (W^T).  C: MxN fp32.
#define BM 128
#define BK 64

template <int BNv>
__global__ __launch_bounds__(256) void gemm_bf16_kernel(const bf16_t* __restrict__ A,
    const bf16_t* __restrict__ B, float* __restrict__ C, int M, int N, int K) {
  constexpr int NF = BNv / 32;             // N-frags per wave
  constexpr int BITER = BNv * 8 / 256;     // B-staging chunks per thread
  __shared__ __attribute__((aligned(16))) bf16_t aL[BM * BK];
  __shared__ __attribute__((aligned(16))) bf16_t bL[BNv * BK];
  const int tid = threadIdx.x;
  const int wave = tid >> 6, lane = tid & 63;
  const int wr = wave >> 1, wc = wave & 1;
  const int l15 = lane & 15, l4 = lane >> 4;
  const int bm = blockIdx.y * BM, bn = blockIdx.x * BNv;

  f32x4 zero = {0.f, 0.f, 0.f, 0.f};
  f32x4 acc[4][NF];
#pragma unroll
  for (int m = 0; m < 4; ++m)
#pragma unroll
    for (int n = 0; n < NF; ++n) acc[m][n] = zero;

  const bf16_t* aSrc[4];
  bf16_t* aDst[4];
#pragma unroll
  for (int i = 0; i < 4; ++i) {
    int ci = i * 256 + tid;
    int r = ci >> 3;
    int cl = (ci & 7) ^ (r & 7);
    aSrc[i] = A + (size_t)(bm + r) * K + cl * 8;
    aDst[i] = aL + (i * 256 + wave * 64) * 8;
  }
  const bf16_t* bSrc[BITER];
  bf16_t* bDst[BITER];
#pragma unroll
  for (int i = 0; i < BITER; ++i) {
    int ci = i * 256 + tid;
    int r = ci >> 3;
    int cl = (ci & 7) ^ (r & 7);
    bSrc[i] = B + (size_t)(bn + r) * K + cl * 8;
    bDst[i] = bL + (i * 256 + wave * 64) * 8;
  }

  for (int kt = 0; kt < K; kt += BK) {
#pragma unroll
    for (int i = 0; i < 4; ++i) gload_lds16(aSrc[i] + kt, aDst[i]);
#pragma unroll
    for (int i = 0; i < BITER; ++i) gload_lds16(bSrc[i] + kt, bDst[i]);
    __syncthreads();
#pragma unroll
    for (int t = 0; t < 2; ++t) {
      bf16x8 af[4], bfr[NF];
#pragma unroll
      for (int f = 0; f < 4; ++f) {
        int Ra = wr * 64 + f * 16 + l15;
        int ca = (t * 4 + l4) ^ (Ra & 7);
        af[f] = *reinterpret_cast<const bf16x8*>(aL + Ra * 64 + ca * 8);
      }
#pragma unroll
      for (int f = 0; f < NF; ++f) {
        int Rb = wc * (BNv / 2) + f * 16 + l15;
        int cb = (t * 4 + l4) ^ (Rb & 7);
        bfr[f] = *reinterpret_cast<const bf16x8*>(bL + Rb * 64 + cb * 8);
      }
      __builtin_amdgcn_s_setprio(1);
#pragma unroll
      for (int m = 0; m < 4; ++m)
#pragma unroll
        for (int n = 0; n < NF; ++n) acc[m][n] = MFMA16(af[m], bfr[n], acc[m][n]);
      __builtin_amdgcn_s_setprio(0);
    }
    __syncthreads();
  }

#pragma unroll
  for (int m = 0; m < 4; ++m) {
    int row0 = bm + wr * 64 + m * 16 + l4 * 4;
#pragma unroll
    for (int n = 0; n < NF; ++n) {
      int col = bn + wc * (BNv / 2) + n * 16 + l15;
#pragma unroll
      for (int r = 0; r < 4; ++r) C[(size_t)(row0 + r) * N + col] = acc[m][n][r];
    }
  }
}

// ---------------------------------------------------------------- differential flash attention
// Swapped-operand: S^T = mfma(K, Q), q = lane (col), kv = regs. Q pre-scaled by SC_Q.
// Grid: 256 blocks (h = b>>4, pr = b&15); each block processes q-tile 31-pr THEN pr
// sequentially -> exactly 33 KV-tile iterations per block, balanced regardless of
// dispatch order (R3-proven). LDS = 72 KiB (kB 32 + vB 32 + pS 8) so TWO blocks/CU
// fit in the 160 KiB pool with slack (R7/R9 falsified 2x80KiB packing).
// Per iteration: QK1 -> sm1 -> PV1 -> QK2 -> sm2 -> PV2, pS[wave] reused per half
// (within-wave DS ordering covers the RAW/WAR; only one score set live at a time).
__global__ __launch_bounds__(256) void diff_attn_kernel(const bf16_t* __restrict__ Qb,
    const bf16_t* __restrict__ Kb, const bf16_t* __restrict__ VTb,
    const float* __restrict__ lambda_param, bf16_t* __restrict__ attn) {
  const int h = blockIdx.x >> 4;
  const int pr = blockIdx.x & 15;
  const int kvh = h >> 2;  // REP = 4
  const int tid = threadIdx.x, wave = tid >> 6, lane = tid & 63;
  const int l15 = lane & 15, l4 = lane >> 4;

  __shared__ __attribute__((aligned(16))) bf16_t kB[2][64 * 128];   // 32 KiB
  __shared__ __attribute__((aligned(16))) bf16_t vB[2][64 * 128];   // 32 KiB
  __shared__ __attribute__((aligned(16))) bf16_t pS[4][16 * 64];    // 8 KiB (one half at a time)

  const bf16_t* kBase = Kb + (size_t)kvh * S_LEN * HD_;
  const bf16_t* vBase = VTb + (size_t)kvh * HD_ * S_LEN;
  int kOff[4], vOff[4], dOff[4];
#pragma unroll
  for (int i = 0; i < 4; ++i) {
    int ci = i * 256 + tid;
    int kr = ci >> 4;
    kOff[i] = kr * HD_ + (((ci & 15) ^ (kr & 7)) * 8);
    int vr = ci >> 3;
    vOff[i] = vr * S_LEN + (((ci & 7) ^ (vr & 7)) * 8);
    dOff[i] = (i * 256 + wave * 64) * 8;
  }

  const float lam = 1.f / (1.f + __expf(-lambda_param[h]));
  const f32x4 zero = {0.f, 0.f, 0.f, 0.f};

  for (int ph = 0; ph < 2; ++ph) {
    const int jt = (ph == 0) ? (31 - pr) : pr;  // heavy tile first
    const int q0 = jt * 64;
    const int qg = q0 + wave * 16 + l15;  // this lane's q row (col of S^T)

    const bf16_t* qp = Qb + ((size_t)h * S_LEN + qg) * HD_;
    bf16x8 qf[4];
#pragma unroll
    for (int f = 0; f < 4; ++f) qf[f] = *reinterpret_cast<const bf16x8*>(qp + f * 32 + l4 * 8);

    f32x4 o1[8], o2[8];
#pragma unroll
    for (int n = 0; n < 8; ++n) { o1[n] = zero; o2[n] = zero; }
    float m1 = -__builtin_inff(), m2 = -__builtin_inff(), l1 = 0.f, l2 = 0.f;

    // prologue: stage tile 0
#pragma unroll
    for (int i = 0; i < 4; ++i) gload_lds16(kBase + kOff[i], &kB[0][0] + dOff[i]);
#pragma unroll
    for (int i = 0; i < 4; ++i) gload_lds16(vBase + vOff[i], &vB[0][0] + dOff[i]);
    __syncthreads();

    for (int t = 0; t <= jt; ++t) {
      const int cur = t & 1;
      if (t < jt) {  // prefetch next tile (overlaps with compute)
        const size_t kv0n = (size_t)(t + 1) * 64;
#pragma unroll
        for (int i = 0; i < 4; ++i) gload_lds16(kBase + kv0n * HD_ + kOff[i], &kB[cur ^ 1][0] + dOff[i]);
#pragma unroll
        for (int i = 0; i < 4; ++i) gload_lds16(vBase + kv0n + vOff[i], &vB[cur ^ 1][0] + dOff[i]);
      }
      const bf16_t* kL = &kB[cur][0];
      const bf16_t* vL = &vB[cur][0];
      const int kv0 = t * 64;
      const bool diag = (t == jt);

      // ================= half 1 (hd 0..63) =================
      f32x4 s1[4];
#pragma unroll
      for (int n = 0; n < 4; ++n) s1[n] = zero;
      __builtin_amdgcn_s_setprio(1);
#pragma unroll
      for (int tt = 0; tt < 2; ++tt) {
#pragma unroll
        for (int n = 0; n < 4; ++n) {
          const int Rk = n * 16 + l15;
          bf16x8 kf = *reinterpret_cast<const bf16x8*>(kL + Rk * 128 + (((tt * 4 + l4) ^ (Rk & 7)) * 8));
          s1[n] = MFMA16(kf, qf[tt], s1[n]);
        }
      }
      __builtin_amdgcn_s_setprio(0);
      if (diag) {
#pragma unroll
        for (int n = 0; n < 4; ++n)
#pragma unroll
          for (int r = 0; r < 4; ++r)
            if (kv0 + n * 16 + l4 * 4 + r > qg) s1[n][r] = -1e30f;
      }
      {
        float ma[4];
#pragma unroll
        for (int n = 0; n < 4; ++n)
          ma[n] = fmaxf(fmaxf(s1[n][0], s1[n][1]), fmaxf(s1[n][2], s1[n][3]));
        float tmax = fmaxf(fmaxf(ma[0], ma[1]), fmaxf(ma[2], ma[3]));
        tmax = fmaxf(tmax, __shfl_xor(tmax, 16));
        tmax = fmaxf(tmax, __shfl_xor(tmax, 32));
        if (!__all(tmax <= m1 + 8.f)) {
          const float mn = fmaxf(m1, tmax);
          const float sc = __builtin_exp2f(m1 - mn);
          m1 = mn;
          l1 *= sc;
#pragma unroll
          for (int n = 0; n < 8; ++n) o1[n] *= sc;
        }
        float rsn[4];
#pragma unroll
        for (int n = 0; n < 4; ++n) {
          float e0 = __builtin_exp2f(s1[n][0] - m1);
          float e1 = __builtin_exp2f(s1[n][1] - m1);
          float e2 = __builtin_exp2f(s1[n][2] - m1);
          float e3 = __builtin_exp2f(s1[n][3] - m1);
          rsn[n] = (e0 + e1) + (e2 + e3);
          int cswz = (n * 2 + (l4 >> 1)) ^ (l15 & 7);
          bf16x4 pk = {(__bf16)e0, (__bf16)e1, (__bf16)e2, (__bf16)e3};
          *reinterpret_cast<bf16x4*>(&pS[wave][l15 * 64 + cswz * 8 + (l4 & 1) * 4]) = pk;
        }
        float rs = (rsn[0] + rsn[1]) + (rsn[2] + rsn[3]);
        rs += __shfl_xor(rs, 16);
        rs += __shfl_xor(rs, 32);
        l1 += rs;
      }
      __builtin_amdgcn_s_setprio(1);
#pragma unroll
      for (int kt = 0; kt < 2; ++kt) {
        int cp = ((kt * 4 + l4) ^ (l15 & 7)) * 8;
        bf16x8 pf = *reinterpret_cast<const bf16x8*>(&pS[wave][l15 * 64 + cp]);
#pragma unroll
        for (int n = 0; n < 8; ++n) {
          const int Rv = n * 16 + l15;
          bf16x8 vf = *reinterpret_cast<const bf16x8*>(vL + Rv * 64 + (((kt * 4 + l4) ^ (Rv & 7)) * 8));
          o1[n] = MFMA16(vf, pf, o1[n]);
        }
      }
      __builtin_amdgcn_s_setprio(0);

      // ================= half 2 (hd 64..127) =================
      f32x4 s2[4];
#pragma unroll
      for (int n = 0; n < 4; ++n) s2[n] = zero;
      __builtin_amdgcn_s_setprio(1);
#pragma unroll
      for (int tt = 0; tt < 2; ++tt) {
#pragma unroll
        for (int n = 0; n < 4; ++n) {
          const int Rk = n * 16 + l15;
          bf16x8 kf = *reinterpret_cast<const bf16x8*>(kL + Rk * 128 + (((8 + tt * 4 + l4) ^ (Rk & 7)) * 8));
          s2[n] = MFMA16(kf, qf[2 + tt], s2[n]);
        }
      }
      __builtin_amdgcn_s_setprio(0);
      if (diag) {
#pragma unroll
        for (int n = 0; n < 4; ++n)
#pragma unroll
          for (int r = 0; r < 4; ++r)
            if (kv0 + n * 16 + l4 * 4 + r > qg) s2[n][r] = -1e30f;
      }
      {
        float ma[4];
#pragma unroll
        for (int n = 0; n < 4; ++n)
          ma[n] = fmaxf(fmaxf(s2[n][0], s2[n][1]), fmaxf(s2[n][2], s2[n][3]));
        float tmax = fmaxf(fmaxf(ma[0], ma[1]), fmaxf(ma[2], ma[3]));
        tmax = fmaxf(tmax, __shfl_xor(tmax, 16));
        tmax = fmaxf(tmax, __shfl_xor(tmax, 32));
        if (!__all(tmax <= m2 + 8.f)) {
          const float mn = fmaxf(m2, tmax);
          const float sc = __builtin_exp2f(m2 - mn);
          m2 = mn;
          l2 *= sc;
#pragma unroll
          for (int n = 0; n < 8; ++n) o2[n] *= sc;
        }
        float rsn[4];
#pragma unroll
        for (int n = 0; n < 4; ++n) {
          float e0 = __builtin_exp2f(s2[n][0] - m2);
          float e1 = __builtin_exp2f(s2[n][1] - m2);
          float e2 = __builtin_exp2f(s2[n][2] - m2);
          float e3 = __builtin_exp2f(s2[n][3] - m2);
          rsn[n] = (e0 + e1) + (e2 + e3);
          int cswz = (n * 2 + (l4 >> 1)) ^ (l15 & 7);
          bf16x4 pk = {(__bf16)e0, (__bf16)e1, (__bf16)e2, (__bf16)e3};
          *reinterpret_cast<bf16x4*>(&pS[wave][l15 * 64 + cswz * 8 + (l4 & 1) * 4]) = pk;
        }
        float rs = (rsn[0] + rsn[1]) + (rsn[2] + rsn[3]);
        rs += __shfl_xor(rs, 16);
        rs += __shfl_xor(rs, 32);
        l2 += rs;
      }
      __builtin_amdgcn_s_setprio(1);
#pragma unroll
      for (int kt = 0; kt < 2; ++kt) {
        int cp = ((kt * 4 + l4) ^ (l15 & 7)) * 8;
        bf16x8 pf = *reinterpret_cast<const bf16x8*>(&pS[wave][l15 * 64 + cp]);
#pragma unroll
        for (int n = 0; n < 8; ++n) {
          const int Rv = n * 16 + l15;
          bf16x8 vf = *reinterpret_cast<const bf16x8*>(vL + Rv * 64 + (((kt * 4 + l4) ^ (Rv & 7)) * 8));
          o2[n] = MFMA16(vf, pf, o2[n]);
        }
      }
      __builtin_amdgcn_s_setprio(0);
      __syncthreads();
    }

    // epilogue: O^T[d][q]: lane q=qg, d = n*16 + l4*4 + r
    const float i1 = 1.f / l1, i2 = lam / l2;
    bf16_t* orow = attn + (size_t)qg * D_MODEL + h * HD_;
#pragma unroll
    for (int n = 0; n < 8; ++n) {
      bf16x4 w = {(__bf16)((o1[n][0] * i1 - o2[n][0] * i2) * 0.5f),
                  (__bf16)((o1[n][1] * i1 - o2[n][1] * i2) * 0.5f),
                  (__bf16)((o1[n][2] * i1 - o2[n][2] * i2) * 0.5f),
                  (__bf16)((o1[n][3] * i1 - o2[n][3] * i2) * 0.5f)};
      *reinterpret_cast<bf16x4*>(orow + n * 16 + l4 * 4) = w;
    }
  }
}

// ---------------------------------------------------------------- launch
extern "C" void kernel_launch(void* const* d_in, const int* in_sizes, int n_in,
                              void* d_out, int out_size, void* d_ws, size_t ws_size,
                              hipStream_t stream) {
  const float* x    = (const float*)d_in[0];
  const float* fcos = (const float*)d_in[1];
  const float* fsin = (const float*)d_in[2];
  const float* Wq   = (const float*)d_in[3];
  const float* Wk   = (const float*)d_in[4];
  const float* Wv   = (const float*)d_in[5];
  const float* Wo   = (const float*)d_in[6];
  const float* lam  = (const float*)d_in[7];
  float* out = (float*)d_out;

  // workspace layout (52 MB total, phases overlap dead regions):
  //  [0,8)   xb  -> attnb      [8,20) WqkvT -> Qb/Kb/VT      [20,28) WoT      [28,52) QKV fp32
  char* w = (char*)d_ws;
  bf16_t* xb    = (bf16_t*)(w);
  bf16_t* attnb = (bf16_t*)(w);
  bf16_t* WqkvT = (bf16_t*)(w + (8ull << 20));
  bf16_t* Qb    = (bf16_t*)(w + (8ull << 20));
  bf16_t* Kb    = (bf16_t*)(w + (16ull << 20));
  bf16_t* VT    = (bf16_t*)(w + (18ull << 20));
  bf16_t* WoT   = (bf16_t*)(w + (20ull << 20));
  float*  QKV   = (float*) (w + (28ull << 20));

  cast_x_kernel<<<2048, 256, 0, stream>>>(x, xb, 524288);
  transpose_cast64_kernel<<<dim3(32, 32), 256, 0, stream>>>(Wq, WqkvT, 2048, 2048);
  transpose_cast64_kernel<<<dim3(8, 32), 256, 0, stream>>>(Wk, WqkvT + 2048 * 2048, 512, 2048);
  transpose_cast64_kernel<<<dim3(8, 32), 256, 0, stream>>>(Wv, WqkvT + 2560 * 2048, 512, 2048);
  transpose_cast64_kernel<<<dim3(32, 32), 256, 0, stream>>>(Wo, WoT, 2048, 2048);

  gemm_bf16_kernel<64><<<dim3(48, 16), 256, 0, stream>>>(xb, WqkvT, QKV, 2048, 3072, 2048);

  rope_kernel<<<2048, 256, 0, stream>>>(QKV, fcos, fsin, Qb, Kb);
  transpose_cast64_kernel<<<dim3(8, 32), 256, 0, stream>>>(QKV + 2560, VT, 3072, 2048);

  diff_attn_kernel<<<256, 256, 0, stream>>>(Qb, Kb, VT, lam, attnb);

  gemm_bf16_kernel<64><<<dim3(32, 16), 256, 0, stream>>>(attnb, WoT, out, 2048, 2048, 2048);
}